// Round 1
// baseline (303.246 us; speedup 1.0000x reference)
//
#include <hip/hip_runtime.h>
#include <math.h>

#define B_   8
#define C_   128
#define L_   8192
#define O_   128
#define POS_ 10
#define CHIN 798          // (2*C + POS) * 3
#define TL   128
#define NT   256

// ---------------------------------------------------------------------------
// Mask dtype detection: the harness ABI is ambiguous about how a bool array
// arrives (1-byte bool vs int32 vs int64). Values are random 0/1 over 65536
// elements, so byte patterns disambiguate with certainty:
//   bool  : nonzero bytes at offsets %4 != 0
//   int32 : zeros at %4!=0, nonzero bytes at offset %8 == 4 (odd elements)
//   int64 : nonzero only at offsets %8 == 0
// flag: 1 = byte/bool, 0 = int32, 2 = int64
// ---------------------------------------------------------------------------
__global__ void detect_mask_kernel(const unsigned char* __restrict__ m, int* __restrict__ flag) {
    __shared__ int s_sub, s_mid;
    if (threadIdx.x == 0) { s_sub = 0; s_mid = 0; }
    __syncthreads();
    int a = 0, b = 0;
    const int n = B_ * L_;   // scan only n bytes: valid under every interpretation
    for (int i = threadIdx.x; i < n; i += blockDim.x) {
        unsigned char v = m[i];
        if (v) {
            if (i & 3) a = 1;
            else if ((i & 7) == 4) b = 1;
        }
    }
    if (a) atomicOr(&s_sub, 1);
    if (b) atomicOr(&s_mid, 1);
    __syncthreads();
    if (threadIdx.x == 0) {
        *flag = s_sub ? 1 : (s_mid ? 0 : 2);
    }
}

// ---------------------------------------------------------------------------
// Main kernel: one block = (b, 128-wide l tile), all 128 outputs.
// 256 threads: tid = ot*16 + lt ; each thread owns 8 outputs x 8 positions.
// K-loop: 17 chunks of 16 channels (8 direct, 8 gathered, 1 penc(10)).
// y[b,o,l] = sum_{c,k} W[o,3c+k] * feat[b,c,l+k-1]  (zero-padded) + bias, *mask
// ---------------------------------------------------------------------------
__global__ __launch_bounds__(NT, 2)
void cc_main_kernel(const float* __restrict__ inputs,
                    const int* __restrict__ conn,
                    const unsigned char* __restrict__ mask,
                    const float* __restrict__ W,
                    const float* __restrict__ bias,
                    float* __restrict__ out,
                    const int* __restrict__ mflag_p) {
    __shared__ int   conn_s[TL + 2];
    __shared__ float feat_s[16][132];   // stride 132: 16B-aligned rows
    __shared__ float Ws[48][136];       // stride 136: 16B-aligned, quad-spread banks

    const int b   = blockIdx.y;
    const int l0  = blockIdx.x * TL;
    const int tid = threadIdx.x;
    const int ot  = tid >> 4;          // 0..15
    const int lt  = tid & 15;          // 0..15
    const int o0  = ot * 8;
    const int ll  = lt * 8;

    // conn for this tile incl. halo; -1 marks out-of-range l (zero padding)
    for (int j = tid; j < TL + 2; j += NT) {
        int lg = l0 - 1 + j;
        conn_s[j] = ((unsigned)lg < (unsigned)L_) ? conn[b * L_ + lg] : -1;
    }

    float acc[8][8];
    #pragma unroll
    for (int i = 0; i < 8; ++i)
        #pragma unroll
        for (int j = 0; j < 8; ++j) acc[i][j] = 0.f;

    const int tc = ot;   // staging row
    const int tj = lt;   // staging col phase

    for (int chunk = 0; chunk < 17; ++chunk) {
        const int CN   = (chunk < 16) ? 16 : POS_;
        const int cg0  = chunk * 16;
        const int col0 = 3 * cg0;

        __syncthreads();   // previous chunk's compute done (also covers conn_s)

        // ---- stage W slice: Ws[kk][o] = W[o][col0 + kk], kk in [0, 3*CN)
        {
            const int nw = O_ * CN * 3;
            for (int idx = tid; idx < nw; idx += NT) {
                int o  = idx & 127;
                int kk = idx >> 7;
                Ws[kk][o] = W[o * CHIN + col0 + kk];
            }
        }

        // ---- stage feature rows [CN][TL+2]
        if (chunk < 8) {
            const float* src = inputs + ((size_t)b * C_ + (cg0 + tc)) * L_;
            for (int j = tj; j < TL + 2; j += 16) {
                int lg = l0 - 1 + j;
                feat_s[tc][j] = ((unsigned)lg < (unsigned)L_) ? src[lg] : 0.f;
            }
        } else if (chunk < 16) {
            const float* src = inputs + ((size_t)b * C_ + (cg0 - 128 + tc)) * L_;
            for (int j = tj; j < TL + 2; j += 16) {
                int cj = conn_s[j];
                feat_s[tc][j] = (cj >= 0) ? src[cj] : 0.f;
            }
        } else {
            if (tc < POS_) {
                const float sc = (float)(1 << tc);   // 2^p, exact
                for (int j = tj; j < TL + 2; j += 16) {
                    int cj = conn_s[j];
                    int lg = l0 - 1 + j;
                    float v = 0.f;
                    if (cj >= 0) {
                        float d = (float)(lg - cj);
                        v = sinf((sc * d) / 1000.0f);   // match reference op order
                    }
                    feat_s[tc][j] = v;
                }
            }
        }

        __syncthreads();

        // ---- compute: per channel, 10-wide sliding window, 3 taps, 8x8 outer product
        for (int c = 0; c < CN; ++c) {
            float f[10];
            {
                float4 fa = *(const float4*)&feat_s[c][ll];
                float4 fb = *(const float4*)&feat_s[c][ll + 4];
                float2 fc2 = *(const float2*)&feat_s[c][ll + 8];
                f[0]=fa.x; f[1]=fa.y; f[2]=fa.z; f[3]=fa.w;
                f[4]=fb.x; f[5]=fb.y; f[6]=fb.z; f[7]=fb.w;
                f[8]=fc2.x; f[9]=fc2.y;
            }
            #pragma unroll
            for (int k = 0; k < 3; ++k) {
                const float* wrow = &Ws[c * 3 + k][o0];
                float4 wa = *(const float4*)&wrow[0];
                float4 wb = *(const float4*)&wrow[4];
                float w[8];
                w[0]=wa.x; w[1]=wa.y; w[2]=wa.z; w[3]=wa.w;
                w[4]=wb.x; w[5]=wb.y; w[6]=wb.z; w[7]=wb.w;
                #pragma unroll
                for (int oi = 0; oi < 8; ++oi)
                    #pragma unroll
                    for (int li = 0; li < 8; ++li)
                        acc[oi][li] = fmaf(w[oi], f[li + k], acc[oi][li]);
            }
        }
    }

    // ---- epilogue: bias, mask, store
    const int mflag = *mflag_p;
    const int lbase = l0 + ll;
    float mv[8];
    if (mflag == 1) {
        #pragma unroll
        for (int li = 0; li < 8; ++li)
            mv[li] = mask[b * L_ + lbase + li] ? 1.f : 0.f;
    } else if (mflag == 0) {
        const int* mi = (const int*)mask;
        #pragma unroll
        for (int li = 0; li < 8; ++li)
            mv[li] = mi[b * L_ + lbase + li] ? 1.f : 0.f;
    } else {
        const int* mi = (const int*)mask;   // int64: test low word
        #pragma unroll
        for (int li = 0; li < 8; ++li)
            mv[li] = mi[2 * (b * L_ + lbase + li)] ? 1.f : 0.f;
    }

    #pragma unroll
    for (int oi = 0; oi < 8; ++oi) {
        float bo = bias[o0 + oi];
        float4 r0, r1;
        r0.x = (acc[oi][0] + bo) * mv[0];
        r0.y = (acc[oi][1] + bo) * mv[1];
        r0.z = (acc[oi][2] + bo) * mv[2];
        r0.w = (acc[oi][3] + bo) * mv[3];
        r1.x = (acc[oi][4] + bo) * mv[4];
        r1.y = (acc[oi][5] + bo) * mv[5];
        r1.z = (acc[oi][6] + bo) * mv[6];
        r1.w = (acc[oi][7] + bo) * mv[7];
        float* dst = out + ((size_t)b * O_ + o0 + oi) * L_ + lbase;
        *(float4*)&dst[0] = r0;
        *(float4*)&dst[4] = r1;
    }
}

extern "C" void kernel_launch(void* const* d_in, const int* in_sizes, int n_in,
                              void* d_out, int out_size, void* d_ws, size_t ws_size,
                              hipStream_t stream) {
    const float*         inputs = (const float*)d_in[0];
    const int*           conn   = (const int*)d_in[1];
    const unsigned char* mask   = (const unsigned char*)d_in[2];
    const float*         W      = (const float*)d_in[3];
    const float*         bias   = (const float*)d_in[4];
    float*               out    = (float*)d_out;
    int*                 mflag  = (int*)d_ws;

    detect_mask_kernel<<<1, 256, 0, stream>>>(mask, mflag);

    dim3 grid(L_ / TL, B_);
    cc_main_kernel<<<grid, NT, 0, stream>>>(inputs, conn, mask, W, bias, out, mflag);
}